// Round 5
// baseline (199.662 us; speedup 1.0000x reference)
//
#include <hip/hip_runtime.h>
#include <math.h>

typedef short  short8 __attribute__((ext_vector_type(8)));
typedef float  f32x4  __attribute__((ext_vector_type(4)));

#define ZQ_ELEMS 4194304    // 16*64*64*64
#define KC       1024
#define EPS_HALF 0.005f

// Output layout (fp32, concat): [0,4194304) z_q_st ; [4194304] vq_loss ;
// [4194305, 4259841) indices (as float)
//
// ws layout (bytes):
//   [0,262144)        ushort epack[1024][128]   per code: hi[64] | lo[64]
//   [262144,266240)   float  enorm[1024]
//   [266240,266244)   int    risky_cnt
// risky list lives in d_out's z_q region (dead until vq_gather).

__device__ inline unsigned short bf16_rne(float f) {
    union { float fv; unsigned u; } a; a.fv = f;
    unsigned r = a.u + 0x7FFFu + ((a.u >> 16) & 1u);
    return (unsigned short)(r >> 16);
}
__device__ inline float bf16_to_f(unsigned short h) {
    union { unsigned u; float fv; } a; a.u = ((unsigned)h) << 16;
    return a.fv;
}

__global__ __launch_bounds__(256) void vq_prep(const float* __restrict__ emb,
        unsigned short* __restrict__ epack, float* __restrict__ enorm) {
    const int k = blockIdx.x * 256 + threadIdx.x;   // grid 4
    const float4* e4 = (const float4*)(emb + k * 64);
    float s = 0.f;
#pragma unroll
    for (int j = 0; j < 16; ++j) {
        float4 v = e4[j];
        float vv[4] = {v.x, v.y, v.z, v.w};
        ushort4 hv, lv;
        unsigned short h[4], l[4];
#pragma unroll
        for (int t = 0; t < 4; ++t) {
            s = fmaf(vv[t], vv[t], s);
            h[t] = bf16_rne(vv[t]);
            l[t] = bf16_rne(vv[t] - bf16_to_f(h[t]));
        }
        hv.x = h[0]; hv.y = h[1]; hv.z = h[2]; hv.w = h[3];
        lv.x = l[0]; lv.y = l[1]; lv.z = l[2]; lv.w = l[3];
        *(ushort4*)(epack + k * 128 + j * 4)      = hv;
        *(ushort4*)(epack + k * 128 + 64 + j * 4) = lv;
    }
    enorm[k] = s;
}

// Block 512 = 8 waves = 2 pixel-halves(32 px) x 4 code-quarters(256 codes). Grid 1024.
#define BLOAD(c, B0, B1, B2, B3, EN) {                          \
    const int code_ = chbase + (c) * 16 + col;                  \
    const short8* p_ = ep8 + code_ * 16 + g;                    \
    B0 = p_[0]; B1 = p_[4]; B2 = p_[8]; B3 = p_[12];            \
    EN = enorm[code_]; }

__global__ __launch_bounds__(512, 4) void vq_scan(const float* __restrict__ z_e,
        const unsigned short* __restrict__ epack, const float* __restrict__ enorm,
        float* __restrict__ out, int* __restrict__ risky_cnt, int* __restrict__ risky) {
    const int tid  = threadIdx.x;
    const int lane = tid & 63;
    const int col  = lane & 15;
    const int g    = lane >> 4;
    const int wv   = __builtin_amdgcn_readfirstlane(tid >> 6);
    const int ph   = wv >> 2;          // pixel half (0/1)
    const int qt   = wv & 3;           // code quarter (0..3)
    const int pblk = blockIdx.x * 64;
    const int chbase = qt * 256;

    __shared__ __align__(16) unsigned short afrag[8192];   // 64 px x (hi64|lo64)
    __shared__ float sb1[8][32], sb2[8][32];
    __shared__ int   sk1[8][32];

    // ---- cooperative A conversion: thread = (pixel lp, dim-group dg), once per block
    {
        const int lp = tid & 63;
        const int dg = tid >> 6;                    // 0..7 (dims dg*8..+8)
        const int pglob = pblk + lp;
        const float* zb = z_e + (pglob >> 12) * 262144 + (pglob & 4095);
        short8 H, L;
#pragma unroll
        for (int j = 0; j < 8; ++j) {
            float v = zb[(dg * 8 + j) * 4096];
            unsigned short h = bf16_rne(v);
            H[j] = (short)h;
            L[j] = (short)bf16_rne(v - bf16_to_f(h));
        }
        const int sw = (dg * 8) ^ ((lp & 7) << 3);  // XOR swizzle within 64-ushort block
        *(short8*)&afrag[lp * 128 + sw]      = H;
        *(short8*)&afrag[lp * 128 + 64 + sw] = L;
    }
    __syncthreads();

    // ---- fragments from LDS: 2 tiles x hi/lo x 2 k-chunks
    short8 fh[2][2], fl[2][2];
#pragma unroll
    for (int q = 0; q < 2; ++q) {
        const int lp = ph * 32 + q * 16 + col;
        const int sx = (lp & 7) << 3;
#pragma unroll
        for (int c2 = 0; c2 < 2; ++c2) {
            const int sw = (c2 * 32 + g * 8) ^ sx;
            fh[q][c2] = *(const short8*)&afrag[lp * 128 + sw];
            fl[q][c2] = *(const short8*)&afrag[lp * 128 + 64 + sw];
        }
    }

    float b1[2][4], b2[2][4]; int k1[2][4];
#pragma unroll
    for (int q = 0; q < 2; ++q)
#pragma unroll
        for (int r = 0; r < 4; ++r) { b1[q][r] = -INFINITY; b2[q][r] = -INFINITY; k1[q][r] = 0; }

    const short8* ep8 = (const short8*)epack;
    const f32x4 zero4 = {0.f, 0.f, 0.f, 0.f};
    short8 bc0, bc1, bc2, bc3, bn0, bn1, bn2, bn3;
    float enc, enn;
    BLOAD(0, bc0, bc1, bc2, bc3, enc);

#pragma unroll 2
    for (int c = 0; c < 16; ++c) {
        BLOAD((c + 1) & 15, bn0, bn1, bn2, bn3, enn);
        const int codec = chbase + c * 16 + col;
        const float enh = -0.5f * enc;
#pragma unroll
        for (int q = 0; q < 2; ++q) {
            f32x4 aA, aB;   // two independent 3-chains
            aA = __builtin_amdgcn_mfma_f32_16x16x32_bf16(fh[q][0], bc0, zero4, 0, 0, 0);
            aB = __builtin_amdgcn_mfma_f32_16x16x32_bf16(fh[q][1], bc1, zero4, 0, 0, 0);
            aA = __builtin_amdgcn_mfma_f32_16x16x32_bf16(fl[q][0], bc0, aA, 0, 0, 0);
            aB = __builtin_amdgcn_mfma_f32_16x16x32_bf16(fl[q][1], bc1, aB, 0, 0, 0);
            aA = __builtin_amdgcn_mfma_f32_16x16x32_bf16(fh[q][0], bc2, aA, 0, 0, 0);
            aB = __builtin_amdgcn_mfma_f32_16x16x32_bf16(fh[q][1], bc3, aB, 0, 0, 0);
#pragma unroll
            for (int r = 0; r < 4; ++r) {
                float v = (aA[r] + aB[r]) + enh;
                bool better = v > b1[q][r];
                k1[q][r] = better ? codec : k1[q][r];
                b2[q][r] = __builtin_amdgcn_fmed3f(b1[q][r], b2[q][r], v);
                b1[q][r] = fmaxf(b1[q][r], v);
            }
        }
        bc0 = bn0; bc1 = bn1; bc2 = bn2; bc3 = bn3; enc = enn;
    }

    // ---- reduce over 16 code-slots (lane bits 0..3)
#pragma unroll
    for (int s = 1; s < 16; s <<= 1) {
#pragma unroll
        for (int q = 0; q < 2; ++q)
#pragma unroll
            for (int r = 0; r < 4; ++r) {
                float o1 = __shfl_xor(b1[q][r], s, 64);
                float o2 = __shfl_xor(b2[q][r], s, 64);
                int   oi = __shfl_xor(k1[q][r], s, 64);
                bool take = (o1 > b1[q][r]) || (o1 == b1[q][r] && oi < k1[q][r]);
                float nb2 = fmaxf(fminf(b1[q][r], o1), fmaxf(b2[q][r], o2));
                b1[q][r] = take ? o1 : b1[q][r];
                k1[q][r] = take ? oi : k1[q][r];
                b2[q][r] = nb2;
            }
    }

    // ---- 4-quarter merge via LDS
    if (col == 0) {
#pragma unroll
        for (int q = 0; q < 2; ++q)
#pragma unroll
            for (int r = 0; r < 4; ++r) {
                const int lp32 = q * 16 + g * 4 + r;
                sb1[wv][lp32] = b1[q][r]; sb2[wv][lp32] = b2[q][r]; sk1[wv][lp32] = k1[q][r];
            }
    }
    __syncthreads();
    if (qt == 0 && col == 0) {
#pragma unroll
        for (int q = 0; q < 2; ++q)
#pragma unroll
            for (int r = 0; r < 4; ++r) {
                const int lp32 = q * 16 + g * 4 + r;
                float B1 = b1[q][r], B2 = b2[q][r]; int K1 = k1[q][r];
#pragma unroll
                for (int j = 1; j < 4; ++j) {     // quarters ascend: strict > keeps lowest code
                    float o1 = sb1[ph * 4 + j][lp32], o2 = sb2[ph * 4 + j][lp32];
                    int   oi = sk1[ph * 4 + j][lp32];
                    float nb2 = fmaxf(fminf(B1, o1), fmaxf(B2, o2));
                    if (o1 > B1) { B1 = o1; K1 = oi; }
                    B2 = nb2;
                }
                const int pix = pblk + ph * 32 + lp32;
                out[ZQ_ELEMS + 1 + pix] = (float)K1;
                if (B1 - B2 < EPS_HALF) {
                    int pos = atomicAdd(risky_cnt, 1);
                    risky[pos] = pix;
                }
            }
    }
}

// Exact fp64 rescore: one wave per flagged item. Grid 256 (1024 waves).
__global__ __launch_bounds__(256) void vq_rescore(const float* __restrict__ z_e,
        const float* __restrict__ emb, float* __restrict__ out,
        const int* __restrict__ cnt, const int* __restrict__ list) {
    const int lane = threadIdx.x & 63;
    const int wid  = (blockIdx.x * 256 + threadIdx.x) >> 6;
    const int nw   = gridDim.x * 4;
    float* idxp = out + ZQ_ELEMS + 1;
    const int n = *cnt;
    for (int item = wid; item < n; item += nw) {
        const int pix = list[item];
        const float* zb = z_e + (pix >> 12) * 262144 + (pix & 4095);
        float f[64];
#pragma unroll
        for (int d = 0; d < 64; ++d) f[d] = zb[d * 4096];
        double best = INFINITY; int bk = KC;
        for (int j = 0; j < 16; ++j) {
            const int k = j * 64 + lane;
            const float* e = emb + k * 64;
            double a0 = 0.0, a1 = 0.0;
#pragma unroll
            for (int d = 0; d < 64; d += 2) {
                double d0 = (double)f[d]     - (double)e[d];
                double d1 = (double)f[d + 1] - (double)e[d + 1];
                a0 = fma(d0, d0, a0);
                a1 = fma(d1, d1, a1);
            }
            double acc = a0 + a1;
            if (acc < best || (acc == best && k < bk)) { best = acc; bk = k; }
        }
        for (int off = 32; off; off >>= 1) {
            double ov = __shfl_down(best, off, 64);
            int    oi = __shfl_down(bk, off, 64);
            if (ov < best || (ov == best && oi < bk)) { best = ov; bk = oi; }
        }
        if (lane == 0) idxp[pix] = (float)bk;
    }
}

// Dim-major gather + fused loss accumulation. Grid 4096.
__global__ __launch_bounds__(256) void vq_gather(
        const float* __restrict__ z_e, const float* __restrict__ emb,
        float* __restrict__ out) {
    const int E = (blockIdx.x * 256 + threadIdx.x) * 4;
    const int b = E >> 18, d = (E >> 12) & 63, hw = E & 4095;
    const int pixbase = (b << 12) + hw;
    const float* idxp = out + ZQ_ELEMS + 1;
    float4 z = *(const float4*)(z_e + E);
    int k0 = (int)idxp[pixbase + 0];
    int k1 = (int)idxp[pixbase + 1];
    int k2 = (int)idxp[pixbase + 2];
    int k3 = (int)idxp[pixbase + 3];
    float4 q;
    q.x = emb[k0 * 64 + d]; q.y = emb[k1 * 64 + d];
    q.z = emb[k2 * 64 + d]; q.w = emb[k3 * 64 + d];
    *(float4*)(out + E) = q;
    float d0 = q.x - z.x, d1 = q.y - z.y, d2 = q.z - z.z, d3 = q.w - z.w;
    float ss = d0 * d0 + d1 * d1 + d2 * d2 + d3 * d3;
    for (int off = 32; off; off >>= 1) ss += __shfl_down(ss, off, 64);
    __shared__ float sred[4];
    if ((threadIdx.x & 63) == 0) sred[threadIdx.x >> 6] = ss;
    __syncthreads();
    if (threadIdx.x == 0) {
        float blocksum = (sred[0] + sred[1]) + (sred[2] + sred[3]);
        atomicAdd(out + ZQ_ELEMS, blocksum * (1.25f / (float)ZQ_ELEMS));
    }
}

extern "C" void kernel_launch(void* const* d_in, const int* in_sizes, int n_in,
                              void* d_out, int out_size, void* d_ws, size_t ws_size,
                              hipStream_t stream) {
    const float* z_e = (const float*)d_in[0];
    const float* emb = (const float*)d_in[1];
    float* out = (float*)d_out;
    char* ws = (char*)d_ws;
    unsigned short* epack = (unsigned short*)ws;
    float* enorm     = (float*)(ws + 262144);
    int*   risky_cnt = (int*)(ws + 266240);
    int*   risky     = (int*)out;               // z_q region, dead until vq_gather

    hipMemsetAsync(risky_cnt, 0, 4, stream);
    hipMemsetAsync(out + ZQ_ELEMS, 0, sizeof(float), stream);   // loss accumulator
    vq_prep<<<4, 256, 0, stream>>>(emb, epack, enorm);
    vq_scan<<<1024, 512, 0, stream>>>(z_e, epack, enorm, out, risky_cnt, risky);
    vq_rescore<<<256, 256, 0, stream>>>(z_e, emb, out, risky_cnt, risky);
    vq_gather<<<4096, 256, 0, stream>>>(z_e, emb, out);
}

// Round 6
// 154.263 us; speedup vs baseline: 1.2943x; 1.2943x over previous
//
#include <hip/hip_runtime.h>
#include <math.h>

typedef short  short8 __attribute__((ext_vector_type(8)));
typedef float  f32x4  __attribute__((ext_vector_type(4)));

#define ZQ_ELEMS 4194304    // 16*64*64*64
#define KC       1024
#define EPS_HALF 0.005f

// Output layout (fp32, concat): [0,4194304) z_q_st ; [4194304] vq_loss ;
// [4194305, 4259841) indices (as float)
//
// ws layout (bytes):
//   [0,262144)        ushort epack[1024][128]   per code: hi[64] | lo[64]
//   [262144,266240)   float  enorm[1024]
//   [266240,266244)   int    risky_cnt
// risky list lives in d_out's z_q region (dead until vq_gather).

__device__ inline unsigned short bf16_rne(float f) {
    union { float fv; unsigned u; } a; a.fv = f;
    unsigned r = a.u + 0x7FFFu + ((a.u >> 16) & 1u);
    return (unsigned short)(r >> 16);
}
__device__ inline float bf16_to_f(unsigned short h) {
    union { unsigned u; float fv; } a; a.u = ((unsigned)h) << 16;
    return a.fv;
}

__global__ __launch_bounds__(256) void vq_prep(const float* __restrict__ emb,
        unsigned short* __restrict__ epack, float* __restrict__ enorm,
        int* __restrict__ risky_cnt, float* __restrict__ out) {
    const int k = blockIdx.x * 256 + threadIdx.x;   // grid 4
    if (k == 0) { *risky_cnt = 0; out[ZQ_ELEMS] = 0.f; }
    const float4* e4 = (const float4*)(emb + k * 64);
    float s = 0.f;
#pragma unroll
    for (int j = 0; j < 16; ++j) {
        float4 v = e4[j];
        float vv[4] = {v.x, v.y, v.z, v.w};
        ushort4 hv, lv;
        unsigned short h[4], l[4];
#pragma unroll
        for (int t = 0; t < 4; ++t) {
            s = fmaf(vv[t], vv[t], s);
            h[t] = bf16_rne(vv[t]);
            l[t] = bf16_rne(vv[t] - bf16_to_f(h[t]));
        }
        hv.x = h[0]; hv.y = h[1]; hv.z = h[2]; hv.w = h[3];
        lv.x = l[0]; lv.y = l[1]; lv.z = l[2]; lv.w = l[3];
        *(ushort4*)(epack + k * 128 + j * 4)      = hv;
        *(ushort4*)(epack + k * 128 + 64 + j * 4) = lv;
    }
    enorm[k] = s;
}

// Block 256 = 4 waves = 1 pixel-group(64 px) x 4 code-quarters(256 codes). Grid 1024.
#define BLOAD(c, B0, B1, B2, B3, EN) {                          \
    const int code_ = chbase + (c) * 16 + col;                  \
    const short8* p_ = ep8 + code_ * 16 + g;                    \
    B0 = p_[0]; B1 = p_[4]; B2 = p_[8]; B3 = p_[12];            \
    EN = enorm[code_]; }

__global__ __launch_bounds__(256) void vq_scan(const float* __restrict__ z_e,
        const unsigned short* __restrict__ epack, const float* __restrict__ enorm,
        float* __restrict__ out, int* __restrict__ risky_cnt, int* __restrict__ risky) {
    const int lane = threadIdx.x & 63;
    const int col  = lane & 15;
    const int g    = lane >> 4;
    const int qt   = __builtin_amdgcn_readfirstlane(threadIdx.x >> 6);  // code quarter
    const int pblk = blockIdx.x * 64;
    const int chbase = qt * 256;

    // ---- A fragments: 4 tiles of 16 pixels, hi/lo split, 2 k-chunks (per wave)
    short8 fh[4][2], fl[4][2];
#pragma unroll
    for (int q = 0; q < 4; ++q) {
        const int p = pblk + q * 16 + col;
        const float* zb = z_e + (p >> 12) * 262144 + (p & 4095);
#pragma unroll
        for (int j = 0; j < 8; ++j) {
            float v0 = zb[(g * 8 + j) * 4096];
            float v1 = zb[(32 + g * 8 + j) * 4096];
            unsigned short h0 = bf16_rne(v0);
            unsigned short h1 = bf16_rne(v1);
            fh[q][0][j] = (short)h0; fl[q][0][j] = (short)bf16_rne(v0 - bf16_to_f(h0));
            fh[q][1][j] = (short)h1; fl[q][1][j] = (short)bf16_rne(v1 - bf16_to_f(h1));
        }
    }

    float b1[4][4], b2[4][4]; int k1[4][4];
#pragma unroll
    for (int q = 0; q < 4; ++q)
#pragma unroll
        for (int r = 0; r < 4; ++r) { b1[q][r] = -INFINITY; b2[q][r] = -INFINITY; k1[q][r] = 0; }

    const short8* ep8 = (const short8*)epack;
    const f32x4 zero4 = {0.f, 0.f, 0.f, 0.f};
    short8 bc0, bc1, bc2, bc3, bn0, bn1, bn2, bn3;
    float enc, enn;
    BLOAD(0, bc0, bc1, bc2, bc3, enc);

#pragma unroll 2
    for (int c = 0; c < 16; ++c) {
        BLOAD((c + 1) & 15, bn0, bn1, bn2, bn3, enn);
        const int codec = chbase + c * 16 + col;
        const float enh = -0.5f * enc;
        const f32x4 enh4 = {enh, enh, enh, enh};
#pragma unroll
        for (int q = 0; q < 4; ++q) {
            // two independent 3-chains; -0.5*enorm pre-folded into chain B's C-init
            f32x4 aA, aB;
            aA = __builtin_amdgcn_mfma_f32_16x16x32_bf16(fh[q][0], bc0, zero4, 0, 0, 0);
            aB = __builtin_amdgcn_mfma_f32_16x16x32_bf16(fh[q][1], bc1, enh4, 0, 0, 0);
            aA = __builtin_amdgcn_mfma_f32_16x16x32_bf16(fl[q][0], bc0, aA, 0, 0, 0);
            aB = __builtin_amdgcn_mfma_f32_16x16x32_bf16(fl[q][1], bc1, aB, 0, 0, 0);
            aA = __builtin_amdgcn_mfma_f32_16x16x32_bf16(fh[q][0], bc2, aA, 0, 0, 0);
            aB = __builtin_amdgcn_mfma_f32_16x16x32_bf16(fh[q][1], bc3, aB, 0, 0, 0);
#pragma unroll
            for (int r = 0; r < 4; ++r) {
                float v = aA[r] + aB[r];
                bool better = v > b1[q][r];
                k1[q][r] = better ? codec : k1[q][r];
                b2[q][r] = __builtin_amdgcn_fmed3f(b1[q][r], b2[q][r], v);
                b1[q][r] = fmaxf(b1[q][r], v);
            }
        }
        bc0 = bn0; bc1 = bn1; bc2 = bn2; bc3 = bn3; enc = enn;
    }

    // ---- reduce over 16 code-slots (lane bits 0..3)
#pragma unroll
    for (int s = 1; s < 16; s <<= 1) {
#pragma unroll
        for (int q = 0; q < 4; ++q)
#pragma unroll
            for (int r = 0; r < 4; ++r) {
                float o1 = __shfl_xor(b1[q][r], s, 64);
                float o2 = __shfl_xor(b2[q][r], s, 64);
                int   oi = __shfl_xor(k1[q][r], s, 64);
                bool take = (o1 > b1[q][r]) || (o1 == b1[q][r] && oi < k1[q][r]);
                float nb2 = fmaxf(fminf(b1[q][r], o1), fmaxf(b2[q][r], o2));
                b1[q][r] = take ? o1 : b1[q][r];
                k1[q][r] = take ? oi : k1[q][r];
                b2[q][r] = nb2;
            }
    }

    // ---- 4-quarter merge via LDS (quarters ascend: strict > keeps lowest code)
    __shared__ float sb1[4][64], sb2[4][64];
    __shared__ int   sk1[4][64];
    if (col == 0) {
#pragma unroll
        for (int q = 0; q < 4; ++q)
#pragma unroll
            for (int r = 0; r < 4; ++r) {
                const int row = q * 16 + g * 4 + r;
                sb1[qt][row] = b1[q][r]; sb2[qt][row] = b2[q][r]; sk1[qt][row] = k1[q][r];
            }
    }
    __syncthreads();
    if (qt == 0 && col == 0) {
#pragma unroll
        for (int q = 0; q < 4; ++q)
#pragma unroll
            for (int r = 0; r < 4; ++r) {
                const int row = q * 16 + g * 4 + r;
                float B1 = b1[q][r], B2 = b2[q][r]; int K1 = k1[q][r];
#pragma unroll
                for (int j = 1; j < 4; ++j) {
                    float o1 = sb1[j][row], o2 = sb2[j][row];
                    int   oi = sk1[j][row];
                    float nb2 = fmaxf(fminf(B1, o1), fmaxf(B2, o2));
                    if (o1 > B1) { B1 = o1; K1 = oi; }
                    B2 = nb2;
                }
                const int pix = pblk + row;
                out[ZQ_ELEMS + 1 + pix] = (float)K1;
                if (B1 - B2 < EPS_HALF) {
                    int pos = atomicAdd(risky_cnt, 1);
                    risky[pos] = pix;
                }
            }
    }
}

// Exact fp64 rescore: one wave per flagged item. Grid 256 (1024 waves).
__global__ __launch_bounds__(256) void vq_rescore(const float* __restrict__ z_e,
        const float* __restrict__ emb, float* __restrict__ out,
        const int* __restrict__ cnt, const int* __restrict__ list) {
    const int lane = threadIdx.x & 63;
    const int wid  = (blockIdx.x * 256 + threadIdx.x) >> 6;
    const int nw   = gridDim.x * 4;
    float* idxp = out + ZQ_ELEMS + 1;
    const int n = *cnt;
    for (int item = wid; item < n; item += nw) {
        const int pix = list[item];
        const float* zb = z_e + (pix >> 12) * 262144 + (pix & 4095);
        float f[64];
#pragma unroll
        for (int d = 0; d < 64; ++d) f[d] = zb[d * 4096];
        double best = INFINITY; int bk = KC;
        for (int j = 0; j < 16; ++j) {
            const int k = j * 64 + lane;
            const float* e = emb + k * 64;
            double a0 = 0.0, a1 = 0.0;
#pragma unroll
            for (int d = 0; d < 64; d += 2) {
                double d0 = (double)f[d]     - (double)e[d];
                double d1 = (double)f[d + 1] - (double)e[d + 1];
                a0 = fma(d0, d0, a0);
                a1 = fma(d1, d1, a1);
            }
            double acc = a0 + a1;
            if (acc < best || (acc == best && k < bk)) { best = acc; bk = k; }
        }
        for (int off = 32; off; off >>= 1) {
            double ov = __shfl_down(best, off, 64);
            int    oi = __shfl_down(bk, off, 64);
            if (ov < best || (ov == best && oi < bk)) { best = ov; bk = oi; }
        }
        if (lane == 0) idxp[pix] = (float)bk;
    }
}

// Dim-major gather + fused loss accumulation. Grid 4096.
__global__ __launch_bounds__(256) void vq_gather(
        const float* __restrict__ z_e, const float* __restrict__ emb,
        float* __restrict__ out) {
    const int E = (blockIdx.x * 256 + threadIdx.x) * 4;
    const int b = E >> 18, d = (E >> 12) & 63, hw = E & 4095;
    const int pixbase = (b << 12) + hw;
    const float* idxp = out + ZQ_ELEMS + 1;
    float4 z = *(const float4*)(z_e + E);
    int k0 = (int)idxp[pixbase + 0];
    int k1 = (int)idxp[pixbase + 1];
    int k2 = (int)idxp[pixbase + 2];
    int k3 = (int)idxp[pixbase + 3];
    float4 q;
    q.x = emb[k0 * 64 + d]; q.y = emb[k1 * 64 + d];
    q.z = emb[k2 * 64 + d]; q.w = emb[k3 * 64 + d];
    *(float4*)(out + E) = q;
    float d0 = q.x - z.x, d1 = q.y - z.y, d2 = q.z - z.z, d3 = q.w - z.w;
    float ss = d0 * d0 + d1 * d1 + d2 * d2 + d3 * d3;
    for (int off = 32; off; off >>= 1) ss += __shfl_down(ss, off, 64);
    __shared__ float sred[4];
    if ((threadIdx.x & 63) == 0) sred[threadIdx.x >> 6] = ss;
    __syncthreads();
    if (threadIdx.x == 0) {
        float blocksum = (sred[0] + sred[1]) + (sred[2] + sred[3]);
        atomicAdd(out + ZQ_ELEMS, blocksum * (1.25f / (float)ZQ_ELEMS));
    }
}

extern "C" void kernel_launch(void* const* d_in, const int* in_sizes, int n_in,
                              void* d_out, int out_size, void* d_ws, size_t ws_size,
                              hipStream_t stream) {
    const float* z_e = (const float*)d_in[0];
    const float* emb = (const float*)d_in[1];
    float* out = (float*)d_out;
    char* ws = (char*)d_ws;
    unsigned short* epack = (unsigned short*)ws;
    float* enorm     = (float*)(ws + 262144);
    int*   risky_cnt = (int*)(ws + 266240);
    int*   risky     = (int*)out;               // z_q region, dead until vq_gather

    vq_prep<<<4, 256, 0, stream>>>(emb, epack, enorm, risky_cnt, out);
    vq_scan<<<1024, 256, 0, stream>>>(z_e, epack, enorm, out, risky_cnt, risky);
    vq_rescore<<<256, 256, 0, stream>>>(z_e, emb, out, risky_cnt, risky);
    vq_gather<<<4096, 256, 0, stream>>>(z_e, emb, out);
}

// Round 7
// 107.969 us; speedup vs baseline: 1.8493x; 1.4288x over previous
//
#include <hip/hip_runtime.h>
#include <math.h>

typedef short  short8 __attribute__((ext_vector_type(8)));
typedef float  f32x4  __attribute__((ext_vector_type(4)));

#define ZQ_ELEMS 4194304    // 16*64*64*64
#define KC       1024
#define EPS_HALF 0.005f

// Output layout (fp32, concat): [0,4194304) z_q_st ; [4194304] vq_loss ;
// [4194305, 4259841) indices (as float)
//
// ws layout (bytes):
//   [0,262144)        ushort epack[1024][128]   per code: hi[64] | lo[64]
//   [262144,266240)   float  enorm[1024]
//   [266240,266244)   int    risky_cnt
// risky list lives in d_out's z_q region (dead until vq_gather).

__device__ inline unsigned short bf16_rne(float f) {
    union { float fv; unsigned u; } a; a.fv = f;
    unsigned r = a.u + 0x7FFFu + ((a.u >> 16) & 1u);
    return (unsigned short)(r >> 16);
}
__device__ inline float bf16_to_f(unsigned short h) {
    union { unsigned u; float fv; } a; a.u = ((unsigned)h) << 16;
    return a.fv;
}
// packed (score, 1023-code) ordered compare via f64 max
__device__ inline double dpack(float hi, unsigned lo) {
    return __hiloint2double(__float_as_int(hi), (int)lo);
}
__device__ inline float dhi(double d) { return __int_as_float(__double2hiint(d)); }
__device__ inline unsigned dlo(double d) { return (unsigned)__double2loint(d); }

__global__ __launch_bounds__(256) void vq_prep(const float* __restrict__ emb,
        unsigned short* __restrict__ epack, float* __restrict__ enorm,
        int* __restrict__ risky_cnt, float* __restrict__ out) {
    const int k = blockIdx.x * 256 + threadIdx.x;   // grid 4
    if (k == 0) { *risky_cnt = 0; out[ZQ_ELEMS] = 0.f; }
    const float4* e4 = (const float4*)(emb + k * 64);
    float s = 0.f;
#pragma unroll
    for (int j = 0; j < 16; ++j) {
        float4 v = e4[j];
        float vv[4] = {v.x, v.y, v.z, v.w};
        ushort4 hv, lv;
        unsigned short h[4], l[4];
#pragma unroll
        for (int t = 0; t < 4; ++t) {
            s = fmaf(vv[t], vv[t], s);
            h[t] = bf16_rne(vv[t]);
            l[t] = bf16_rne(vv[t] - bf16_to_f(h[t]));
        }
        hv.x = h[0]; hv.y = h[1]; hv.z = h[2]; hv.w = h[3];
        lv.x = l[0]; lv.y = l[1]; lv.z = l[2]; lv.w = l[3];
        *(ushort4*)(epack + k * 128 + j * 4)      = hv;
        *(ushort4*)(epack + k * 128 + 64 + j * 4) = lv;
    }
    enorm[k] = s;
}

// Block 256 = 4 waves = 4 code-quarters over one 64-px group. Grid 1024.
#define BLOAD(c, B0, B1, B2, B3, EN) {                        \
    const int code_ = chbase + (c) * 16 + col;                \
    const short8* p_ = ep8 + code_ * 16 + g;                  \
    B0 = p_[0]; B1 = p_[4]; B2 = p_[8]; B3 = p_[12];          \
    EN = enorm[code_]; }

__global__ __launch_bounds__(256) void vq_scan(const float* __restrict__ z_e,
        const unsigned short* __restrict__ epack, const float* __restrict__ enorm,
        float* __restrict__ out, int* __restrict__ risky_cnt, int* __restrict__ risky) {
    const int tid  = threadIdx.x;
    const int lane = tid & 63;
    const int col  = lane & 15;
    const int g    = lane >> 4;
    const int qt   = __builtin_amdgcn_readfirstlane(tid >> 6);  // code quarter 0..3
    const int pblk = blockIdx.x * 64;
    const int chbase = qt * 256;

    __shared__ __align__(16) unsigned short afrag[64 * 128];   // 64 px x (hi64|lo64)
    __shared__ double sbst[4][64];
    __shared__ float  sb2l[4][64];

    // ---- cooperative A conversion (ONCE per block): thread = (px, 16-dim group)
    {
        const int lp = tid & 63;
        const int dh = tid >> 6;                 // 0..3 -> dims dh*16..+16
        const int pglob = pblk + lp;
        const float* zb = z_e + (pglob >> 12) * 262144 + (pglob & 4095);
        const int sx = (lp & 7) << 3;
#pragma unroll
        for (int s8 = 0; s8 < 2; ++s8) {
            short8 H, L;
#pragma unroll
            for (int j = 0; j < 8; ++j) {
                float v = zb[(dh * 16 + s8 * 8 + j) * 4096];
                unsigned short h = bf16_rne(v);
                H[j] = (short)h;
                L[j] = (short)bf16_rne(v - bf16_to_f(h));
            }
            const int sw = (dh * 16 + s8 * 8) ^ sx;    // XOR swizzle (bank spread)
            *(short8*)&afrag[lp * 128 + sw]      = H;
            *(short8*)&afrag[lp * 128 + 64 + sw] = L;
        }
    }
    __syncthreads();

    // ---- fragments from LDS: 4 tiles x 2 k-chunks x hi/lo
    short8 fh[4][2], fl[4][2];
#pragma unroll
    for (int q = 0; q < 4; ++q) {
        const int lp = q * 16 + col;
        const int sx = (lp & 7) << 3;
#pragma unroll
        for (int cc = 0; cc < 2; ++cc) {
            const int sw = (cc * 32 + g * 8) ^ sx;
            fh[q][cc] = *(const short8*)&afrag[lp * 128 + sw];
            fl[q][cc] = *(const short8*)&afrag[lp * 128 + 64 + sw];
        }
    }

    double best[4][4];
    float  b2[4][4];
#pragma unroll
    for (int q = 0; q < 4; ++q)
#pragma unroll
        for (int r = 0; r < 4; ++r) { best[q][r] = dpack(-INFINITY, 0u); b2[q][r] = -INFINITY; }

    const short8* ep8 = (const short8*)epack;
    short8 bc0, bc1, bc2, bc3, bn0, bn1, bn2, bn3;
    float enc, enn;
    BLOAD(0, bc0, bc1, bc2, bc3, enc);

#pragma unroll 2
    for (int c = 0; c < 16; ++c) {
        BLOAD((c + 1) & 15, bn0, bn1, bn2, bn3, enn);
        const unsigned codelo = (unsigned)(1023 - (chbase + c * 16 + col));
        const float enh = -0.5f * enc;
        const f32x4 zero4 = {0.f, 0.f, 0.f, 0.f};
        const f32x4 enh4  = {enh, enh, enh, enh};
#pragma unroll
        for (int q = 0; q < 4; ++q) {
            f32x4 aA, aB;   // two independent 3-chains; -0.5*enorm folded into aB C-init
            aA = __builtin_amdgcn_mfma_f32_16x16x32_bf16(fh[q][0], bc0, zero4, 0, 0, 0);
            aB = __builtin_amdgcn_mfma_f32_16x16x32_bf16(fh[q][1], bc1, enh4, 0, 0, 0);
            aA = __builtin_amdgcn_mfma_f32_16x16x32_bf16(fl[q][0], bc0, aA, 0, 0, 0);
            aB = __builtin_amdgcn_mfma_f32_16x16x32_bf16(fl[q][1], bc1, aB, 0, 0, 0);
            aA = __builtin_amdgcn_mfma_f32_16x16x32_bf16(fh[q][0], bc2, aA, 0, 0, 0);
            aB = __builtin_amdgcn_mfma_f32_16x16x32_bf16(fh[q][1], bc3, aB, 0, 0, 0);
#pragma unroll
            for (int r = 0; r < 4; ++r) {
                const float v = aA[r] + aB[r];
                b2[q][r]   = __builtin_amdgcn_fmed3f(dhi(best[q][r]), b2[q][r], v);
                best[q][r] = fmax(best[q][r], dpack(v, codelo));
            }
        }
        bc0 = bn0; bc1 = bn1; bc2 = bn2; bc3 = bn3; enc = enn;
    }

    // ---- reduce over 16 code-slots (lane bits 0..3), packed compare
#pragma unroll
    for (int s = 1; s < 16; s <<= 1) {
#pragma unroll
        for (int q = 0; q < 4; ++q)
#pragma unroll
            for (int r = 0; r < 4; ++r) {
                const double ob = __shfl_xor(best[q][r], s, 64);
                const float  o2 = __shfl_xor(b2[q][r], s, 64);
                b2[q][r]   = __builtin_amdgcn_fmed3f(dhi(best[q][r]), dhi(ob),
                                                     fmaxf(b2[q][r], o2));
                best[q][r] = fmax(best[q][r], ob);
            }
    }

    // ---- 4-quarter merge via LDS
    if (col == 0) {
#pragma unroll
        for (int q = 0; q < 4; ++q)
#pragma unroll
            for (int r = 0; r < 4; ++r) {
                const int row = q * 16 + g * 4 + r;
                sbst[qt][row] = best[q][r];
                sb2l[qt][row] = b2[q][r];
            }
    }
    __syncthreads();
    if (qt == 0 && col == 0) {
#pragma unroll
        for (int q = 0; q < 4; ++q)
#pragma unroll
            for (int r = 0; r < 4; ++r) {
                const int row = q * 16 + g * 4 + r;
                double B = best[q][r];
                float  S = b2[q][r];
#pragma unroll
                for (int j = 1; j < 4; ++j) {
                    const double ob = sbst[j][row];
                    const float  o2 = sb2l[j][row];
                    S = __builtin_amdgcn_fmed3f(dhi(B), dhi(ob), fmaxf(S, o2));
                    B = fmax(B, ob);
                }
                const int pix = pblk + row;
                out[ZQ_ELEMS + 1 + pix] = (float)(1023 - (int)dlo(B));
                if (dhi(B) - S < EPS_HALF) {
                    const int pos = atomicAdd(risky_cnt, 1);
                    risky[pos] = pix;
                }
            }
    }
}

// Exact fp64 rescore: one wave per flagged item. Grid 512 (2048 waves).
__global__ __launch_bounds__(256) void vq_rescore(const float* __restrict__ z_e,
        const float* __restrict__ emb, float* __restrict__ out,
        const int* __restrict__ cnt, const int* __restrict__ list) {
    const int lane = threadIdx.x & 63;
    const int wid  = (blockIdx.x * 256 + threadIdx.x) >> 6;
    const int nw   = gridDim.x * 4;
    float* idxp = out + ZQ_ELEMS + 1;
    const int n = *cnt;
    for (int item = wid; item < n; item += nw) {
        const int pix = list[item];
        const float* zb = z_e + (pix >> 12) * 262144 + (pix & 4095);
        float f[64];
#pragma unroll
        for (int d = 0; d < 64; ++d) f[d] = zb[d * 4096];
        double best = INFINITY; int bk = KC;
        for (int j = 0; j < 16; ++j) {
            const int k = j * 64 + lane;
            const float* e = emb + k * 64;
            double a0 = 0.0, a1 = 0.0;
#pragma unroll
            for (int d = 0; d < 64; d += 2) {
                double d0 = (double)f[d]     - (double)e[d];
                double d1 = (double)f[d + 1] - (double)e[d + 1];
                a0 = fma(d0, d0, a0);
                a1 = fma(d1, d1, a1);
            }
            double acc = a0 + a1;
            if (acc < best || (acc == best && k < bk)) { best = acc; bk = k; }
        }
        for (int off = 32; off; off >>= 1) {
            double ov = __shfl_down(best, off, 64);
            int    oi = __shfl_down(bk, off, 64);
            if (ov < best || (ov == best && oi < bk)) { best = ov; bk = oi; }
        }
        if (lane == 0) idxp[pix] = (float)bk;
    }
}

// Transpose-gather through LDS: block = 64 pixels. Coalesced everywhere. Grid 1024.
__global__ __launch_bounds__(256) void vq_gather(const float* __restrict__ z_e,
        const float* __restrict__ emb, float* __restrict__ out) {
    __shared__ float zq[64][65];       // +1 pad: conflict-free transpose
    const int tid  = threadIdx.x;
    const int lane = tid & 63;
    const int w    = __builtin_amdgcn_readfirstlane(tid >> 6);
    const int pblk = blockIdx.x * 64;
    const int batch = pblk >> 12;
    const int hw0   = pblk & 4095;
    const float* idxp = out + ZQ_ELEMS + 1;

    // phase 1: coalesced codebook-row reads, pixel-major into LDS
#pragma unroll
    for (int i = 0; i < 16; ++i) {
        const int p = w * 16 + i;
        const int k = (int)idxp[pblk + p];     // wave-uniform -> broadcast
        zq[p][lane] = emb[k * 64 + lane];
    }
    __syncthreads();

    // phase 2: (B,D,H,W)-major float4 writes + fused loss
    const int p4 = (tid & 15) * 4;
    const float* zeb = z_e + batch * 262144 + hw0;
    float* ob = out + batch * 262144 + hw0;
    float ss = 0.f;
#pragma unroll
    for (int it = 0; it < 4; ++it) {
        const int d = (tid >> 4) + it * 16;
        float4 q;
        q.x = zq[p4 + 0][d]; q.y = zq[p4 + 1][d];
        q.z = zq[p4 + 2][d]; q.w = zq[p4 + 3][d];
        const float4 z = *(const float4*)(zeb + d * 4096 + p4);
        *(float4*)(ob + d * 4096 + p4) = q;
        const float d0 = q.x - z.x, d1 = q.y - z.y, d2 = q.z - z.z, d3 = q.w - z.w;
        ss += d0 * d0 + d1 * d1 + d2 * d2 + d3 * d3;
    }
    for (int off = 32; off; off >>= 1) ss += __shfl_down(ss, off, 64);
    __shared__ float sred[4];
    if (lane == 0) sred[w] = ss;
    __syncthreads();
    if (tid == 0)
        atomicAdd(out + ZQ_ELEMS,
                  ((sred[0] + sred[1]) + (sred[2] + sred[3])) * (1.25f / (float)ZQ_ELEMS));
}

extern "C" void kernel_launch(void* const* d_in, const int* in_sizes, int n_in,
                              void* d_out, int out_size, void* d_ws, size_t ws_size,
                              hipStream_t stream) {
    const float* z_e = (const float*)d_in[0];
    const float* emb = (const float*)d_in[1];
    float* out = (float*)d_out;
    char* ws = (char*)d_ws;
    unsigned short* epack = (unsigned short*)ws;
    float* enorm     = (float*)(ws + 262144);
    int*   risky_cnt = (int*)(ws + 266240);
    int*   risky     = (int*)out;               // z_q region, dead until vq_gather

    vq_prep<<<4, 256, 0, stream>>>(emb, epack, enorm, risky_cnt, out);
    vq_scan<<<1024, 256, 0, stream>>>(z_e, epack, enorm, out, risky_cnt, risky);
    vq_rescore<<<512, 256, 0, stream>>>(z_e, emb, out, risky_cnt, risky);
    vq_gather<<<1024, 256, 0, stream>>>(z_e, emb, out);
}

// Round 8
// 107.477 us; speedup vs baseline: 1.8577x; 1.0046x over previous
//
#include <hip/hip_runtime.h>
#include <math.h>

typedef short  short8 __attribute__((ext_vector_type(8)));
typedef float  f32x4  __attribute__((ext_vector_type(4)));

#define ZQ_ELEMS 4194304    // 16*64*64*64
#define KC       1024
#define EPS_HALF 0.005f

// Output layout (fp32, concat): [0,4194304) z_q_st ; [4194304] vq_loss ;
// [4194305, 4259841) indices (as float)
//
// ws layout (bytes):
//   [0,262144)        ushort epack[1024][128]   per code: hi[64] | lo[64]
//   [262144,266240)   float  enorm[1024]
//   [266240,266244)   int    risky_cnt
// risky list lives in d_out's z_q region (dead until vq_gather).

__device__ inline unsigned short bf16_rne(float f) {
    union { float fv; unsigned u; } a; a.fv = f;
    unsigned r = a.u + 0x7FFFu + ((a.u >> 16) & 1u);
    return (unsigned short)(r >> 16);
}
__device__ inline float bf16_to_f(unsigned short h) {
    union { unsigned u; float fv; } a; a.u = ((unsigned)h) << 16;
    return a.fv;
}
// packed (score, 1023-code) ordered compare via f64 max
__device__ inline double dpack(float hi, unsigned lo) {
    return __hiloint2double(__float_as_int(hi), (int)lo);
}
__device__ inline float dhi(double d) { return __int_as_float(__double2hiint(d)); }
__device__ inline unsigned dlo(double d) { return (unsigned)__double2loint(d); }

__global__ __launch_bounds__(256) void vq_prep(const float* __restrict__ emb,
        unsigned short* __restrict__ epack, float* __restrict__ enorm,
        int* __restrict__ risky_cnt, float* __restrict__ out) {
    const int k = blockIdx.x * 256 + threadIdx.x;   // grid 4
    if (k == 0) { *risky_cnt = 0; out[ZQ_ELEMS] = 0.f; }
    const float4* e4 = (const float4*)(emb + k * 64);
    float s = 0.f;
#pragma unroll
    for (int j = 0; j < 16; ++j) {
        float4 v = e4[j];
        float vv[4] = {v.x, v.y, v.z, v.w};
        ushort4 hv, lv;
        unsigned short h[4], l[4];
#pragma unroll
        for (int t = 0; t < 4; ++t) {
            s = fmaf(vv[t], vv[t], s);
            h[t] = bf16_rne(vv[t]);
            l[t] = bf16_rne(vv[t] - bf16_to_f(h[t]));
        }
        hv.x = h[0]; hv.y = h[1]; hv.z = h[2]; hv.w = h[3];
        lv.x = l[0]; lv.y = l[1]; lv.z = l[2]; lv.w = l[3];
        *(ushort4*)(epack + k * 128 + j * 4)      = hv;
        *(ushort4*)(epack + k * 128 + 64 + j * 4) = lv;
    }
    enorm[k] = s;
}

// Block 256 = 4 waves = 4 code-quarters over one 64-px group. Grid 1024.
#define BLOAD(c, B0, B1, B2, B3, EN) {                        \
    const int code_ = chbase + (c) * 16 + col;                \
    const short8* p_ = ep8 + code_ * 16 + g;                  \
    B0 = p_[0]; B1 = p_[4]; B2 = p_[8]; B3 = p_[12];          \
    EN = enorm[code_]; }

__global__ __launch_bounds__(256, 2) void vq_scan(const float* __restrict__ z_e,
        const unsigned short* __restrict__ epack, const float* __restrict__ enorm,
        float* __restrict__ out, int* __restrict__ risky_cnt, int* __restrict__ risky) {
    const int tid  = threadIdx.x;
    const int lane = tid & 63;
    const int col  = lane & 15;
    const int g    = lane >> 4;
    const int qt   = __builtin_amdgcn_readfirstlane(tid >> 6);  // code quarter 0..3
    const int pblk = blockIdx.x * 64;
    const int chbase = qt * 256;

    __shared__ __align__(16) unsigned short afrag[64 * 128];   // 64 px x (hi64|lo64)
    __shared__ double sbst[4][64];
    __shared__ float  sb2l[4][64];

    // ---- cooperative A conversion (ONCE per block): thread = (px, 16-dim group)
    {
        const int lp = tid & 63;
        const int dh = tid >> 6;                 // 0..3 -> dims dh*16..+16
        const int pglob = pblk + lp;
        const float* zb = z_e + (pglob >> 12) * 262144 + (pglob & 4095);
        const int sx = (lp & 7) << 3;
#pragma unroll
        for (int s8 = 0; s8 < 2; ++s8) {
            short8 H, L;
#pragma unroll
            for (int j = 0; j < 8; ++j) {
                float v = zb[(dh * 16 + s8 * 8 + j) * 4096];
                unsigned short h = bf16_rne(v);
                H[j] = (short)h;
                L[j] = (short)bf16_rne(v - bf16_to_f(h));
            }
            const int sw = (dh * 16 + s8 * 8) ^ sx;    // XOR swizzle (bank spread)
            *(short8*)&afrag[lp * 128 + sw]      = H;
            *(short8*)&afrag[lp * 128 + 64 + sw] = L;
        }
    }
    __syncthreads();

    // ---- fragments from LDS: 4 tiles x 2 k-chunks x hi/lo
    short8 fh[4][2], fl[4][2];
#pragma unroll
    for (int q = 0; q < 4; ++q) {
        const int lp = q * 16 + col;
        const int sx = (lp & 7) << 3;
#pragma unroll
        for (int cc = 0; cc < 2; ++cc) {
            const int sw = (cc * 32 + g * 8) ^ sx;
            fh[q][cc] = *(const short8*)&afrag[lp * 128 + sw];
            fl[q][cc] = *(const short8*)&afrag[lp * 128 + 64 + sw];
        }
    }

    double best[4][4];
    float  b2[4][4];
#pragma unroll
    for (int q = 0; q < 4; ++q)
#pragma unroll
        for (int r = 0; r < 4; ++r) { best[q][r] = dpack(-INFINITY, 0u); b2[q][r] = -INFINITY; }

    const short8* ep8 = (const short8*)epack;
    short8 bc0, bc1, bc2, bc3, bn0, bn1, bn2, bn3;
    float enc, enn;
    BLOAD(0, bc0, bc1, bc2, bc3, enc);

#pragma unroll 2
    for (int c = 0; c < 16; ++c) {
        BLOAD((c + 1) & 15, bn0, bn1, bn2, bn3, enn);
        const unsigned codelo = (unsigned)(1023 - (chbase + c * 16 + col));
        const float enh = -0.5f * enc;
        const f32x4 zero4 = {0.f, 0.f, 0.f, 0.f};
        const f32x4 enh4  = {enh, enh, enh, enh};
#pragma unroll
        for (int q = 0; q < 4; ++q) {
            f32x4 aA, aB;   // two independent 3-chains; -0.5*enorm folded into aB C-init
            aA = __builtin_amdgcn_mfma_f32_16x16x32_bf16(fh[q][0], bc0, zero4, 0, 0, 0);
            aB = __builtin_amdgcn_mfma_f32_16x16x32_bf16(fh[q][1], bc1, enh4, 0, 0, 0);
            aA = __builtin_amdgcn_mfma_f32_16x16x32_bf16(fl[q][0], bc0, aA, 0, 0, 0);
            aB = __builtin_amdgcn_mfma_f32_16x16x32_bf16(fl[q][1], bc1, aB, 0, 0, 0);
            aA = __builtin_amdgcn_mfma_f32_16x16x32_bf16(fh[q][0], bc2, aA, 0, 0, 0);
            aB = __builtin_amdgcn_mfma_f32_16x16x32_bf16(fh[q][1], bc3, aB, 0, 0, 0);
#pragma unroll
            for (int r = 0; r < 4; ++r) {
                const float v = aA[r] + aB[r];
                b2[q][r]   = __builtin_amdgcn_fmed3f(dhi(best[q][r]), b2[q][r], v);
                best[q][r] = fmax(best[q][r], dpack(v, codelo));
            }
        }
        bc0 = bn0; bc1 = bn1; bc2 = bn2; bc3 = bn3; enc = enn;
    }

    // ---- reduce over 16 code-slots (lane bits 0..3), packed compare
#pragma unroll
    for (int s = 1; s < 16; s <<= 1) {
#pragma unroll
        for (int q = 0; q < 4; ++q)
#pragma unroll
            for (int r = 0; r < 4; ++r) {
                const double ob = __shfl_xor(best[q][r], s, 64);
                const float  o2 = __shfl_xor(b2[q][r], s, 64);
                b2[q][r]   = __builtin_amdgcn_fmed3f(dhi(best[q][r]), dhi(ob),
                                                     fmaxf(b2[q][r], o2));
                best[q][r] = fmax(best[q][r], ob);
            }
    }

    // ---- 4-quarter merge via LDS
    if (col == 0) {
#pragma unroll
        for (int q = 0; q < 4; ++q)
#pragma unroll
            for (int r = 0; r < 4; ++r) {
                const int row = q * 16 + g * 4 + r;
                sbst[qt][row] = best[q][r];
                sb2l[qt][row] = b2[q][r];
            }
    }
    __syncthreads();
    if (qt == 0 && col == 0) {
#pragma unroll
        for (int q = 0; q < 4; ++q)
#pragma unroll
            for (int r = 0; r < 4; ++r) {
                const int row = q * 16 + g * 4 + r;
                double B = best[q][r];
                float  S = b2[q][r];
#pragma unroll
                for (int j = 1; j < 4; ++j) {
                    const double ob = sbst[j][row];
                    const float  o2 = sb2l[j][row];
                    S = __builtin_amdgcn_fmed3f(dhi(B), dhi(ob), fmaxf(S, o2));
                    B = fmax(B, ob);
                }
                const int pix = pblk + row;
                out[ZQ_ELEMS + 1 + pix] = (float)(1023 - (int)dlo(B));
                if (dhi(B) - S < EPS_HALF) {
                    const int pos = atomicAdd(risky_cnt, 1);
                    risky[pos] = pix;
                }
            }
    }
}

// Exact fp64 rescore: one wave per flagged item. Grid 512 (2048 waves).
__global__ __launch_bounds__(256) void vq_rescore(const float* __restrict__ z_e,
        const float* __restrict__ emb, float* __restrict__ out,
        const int* __restrict__ cnt, const int* __restrict__ list) {
    const int lane = threadIdx.x & 63;
    const int wid  = (blockIdx.x * 256 + threadIdx.x) >> 6;
    const int nw   = gridDim.x * 4;
    float* idxp = out + ZQ_ELEMS + 1;
    const int n = *cnt;
    for (int item = wid; item < n; item += nw) {
        const int pix = list[item];
        const float* zb = z_e + (pix >> 12) * 262144 + (pix & 4095);
        float f[64];
#pragma unroll
        for (int d = 0; d < 64; ++d) f[d] = zb[d * 4096];
        double best = INFINITY; int bk = KC;
        for (int j = 0; j < 16; ++j) {
            const int k = j * 64 + lane;
            const float* e = emb + k * 64;
            double a0 = 0.0, a1 = 0.0;
#pragma unroll
            for (int d = 0; d < 64; d += 2) {
                double d0 = (double)f[d]     - (double)e[d];
                double d1 = (double)f[d + 1] - (double)e[d + 1];
                a0 = fma(d0, d0, a0);
                a1 = fma(d1, d1, a1);
            }
            double acc = a0 + a1;
            if (acc < best || (acc == best && k < bk)) { best = acc; bk = k; }
        }
        for (int off = 32; off; off >>= 1) {
            double ov = __shfl_down(best, off, 64);
            int    oi = __shfl_down(bk, off, 64);
            if (ov < best || (ov == best && oi < bk)) { best = ov; bk = oi; }
        }
        if (lane == 0) idxp[pix] = (float)bk;
    }
}

// Transpose-gather through LDS: block = 64 pixels. Coalesced everywhere. Grid 1024.
__global__ __launch_bounds__(256) void vq_gather(const float* __restrict__ z_e,
        const float* __restrict__ emb, float* __restrict__ out) {
    __shared__ float zq[64][65];       // +1 pad: conflict-free transpose
    const int tid  = threadIdx.x;
    const int lane = tid & 63;
    const int w    = __builtin_amdgcn_readfirstlane(tid >> 6);
    const int pblk = blockIdx.x * 64;
    const int batch = pblk >> 12;
    const int hw0   = pblk & 4095;
    const float* idxp = out + ZQ_ELEMS + 1;

    // phase 1: coalesced codebook-row reads, pixel-major into LDS
#pragma unroll
    for (int i = 0; i < 16; ++i) {
        const int p = w * 16 + i;
        const int k = (int)idxp[pblk + p];     // wave-uniform -> broadcast
        zq[p][lane] = emb[k * 64 + lane];
    }
    __syncthreads();

    // phase 2: (B,D,H,W)-major float4 writes + fused loss
    const int p4 = (tid & 15) * 4;
    const float* zeb = z_e + batch * 262144 + hw0;
    float* ob = out + batch * 262144 + hw0;
    float ss = 0.f;
#pragma unroll
    for (int it = 0; it < 4; ++it) {
        const int d = (tid >> 4) + it * 16;
        float4 q;
        q.x = zq[p4 + 0][d]; q.y = zq[p4 + 1][d];
        q.z = zq[p4 + 2][d]; q.w = zq[p4 + 3][d];
        const float4 z = *(const float4*)(zeb + d * 4096 + p4);
        *(float4*)(ob + d * 4096 + p4) = q;
        const float d0 = q.x - z.x, d1 = q.y - z.y, d2 = q.z - z.z, d3 = q.w - z.w;
        ss += d0 * d0 + d1 * d1 + d2 * d2 + d3 * d3;
    }
    for (int off = 32; off; off >>= 1) ss += __shfl_down(ss, off, 64);
    __shared__ float sred[4];
    if (lane == 0) sred[w] = ss;
    __syncthreads();
    if (tid == 0)
        atomicAdd(out + ZQ_ELEMS,
                  ((sred[0] + sred[1]) + (sred[2] + sred[3])) * (1.25f / (float)ZQ_ELEMS));
}

extern "C" void kernel_launch(void* const* d_in, const int* in_sizes, int n_in,
                              void* d_out, int out_size, void* d_ws, size_t ws_size,
                              hipStream_t stream) {
    const float* z_e = (const float*)d_in[0];
    const float* emb = (const float*)d_in[1];
    float* out = (float*)d_out;
    char* ws = (char*)d_ws;
    unsigned short* epack = (unsigned short*)ws;
    float* enorm     = (float*)(ws + 262144);
    int*   risky_cnt = (int*)(ws + 266240);
    int*   risky     = (int*)out;               // z_q region, dead until vq_gather

    vq_prep<<<4, 256, 0, stream>>>(emb, epack, enorm, risky_cnt, out);
    vq_scan<<<1024, 256, 0, stream>>>(z_e, epack, enorm, out, risky_cnt, risky);
    vq_rescore<<<512, 256, 0, stream>>>(z_e, emb, out, risky_cnt, risky);
    vq_gather<<<1024, 256, 0, stream>>>(z_e, emb, out);
}

// Round 10
// 99.683 us; speedup vs baseline: 2.0030x; 1.0782x over previous
//
#include <hip/hip_runtime.h>
#include <math.h>

typedef short  short8 __attribute__((ext_vector_type(8)));
typedef float  f32x4  __attribute__((ext_vector_type(4)));

#define ZQ_ELEMS 4194304    // 16*64*64*64
#define KC       1024
#define EPS_HALF 0.005f
#define PXB      128

// Output layout (fp32, concat): [0,4194304) z_q_st ; [4194304] vq_loss ;
// [4194305, 4259841) indices (as float)
//
// ws layout (bytes):
//   [0,262144)        ushort epack[1024][128]   per code: hi[64] | lo[64]
//   [262144,266240)   float  enorm[1024]
//   [266240,266244)   int    risky_cnt
//
// d_out z_q region reused as scratch (dead until vq_gather):
//   double pbest[4][65536]  = out floats [0, 524288)
//   float  pb2  [4][65536]  = out floats [524288, 786432)
//   int    risky[<=65536]   = out floats [786432, 851968)

__device__ inline unsigned short bf16_rne(float f) {
    union { float fv; unsigned u; } a; a.fv = f;
    unsigned r = a.u + 0x7FFFu + ((a.u >> 16) & 1u);
    return (unsigned short)(r >> 16);
}
__device__ inline float bf16_to_f(unsigned short h) {
    union { unsigned u; float fv; } a; a.u = ((unsigned)h) << 16;
    return a.fv;
}
// packed (score, 1023-code) ordered compare via f64 max
__device__ inline double dpack(float hi, unsigned lo) {
    return __hiloint2double(__float_as_int(hi), (int)lo);
}
__device__ inline float dhi(double d) { return __int_as_float(__double2hiint(d)); }
__device__ inline unsigned dlo(double d) { return (unsigned)__double2loint(d); }

__global__ __launch_bounds__(256) void vq_prep(const float* __restrict__ emb,
        unsigned short* __restrict__ epack, float* __restrict__ enorm,
        int* __restrict__ risky_cnt, float* __restrict__ out) {
    const int k = blockIdx.x * 256 + threadIdx.x;   // grid 4
    if (k == 0) { *risky_cnt = 0; out[ZQ_ELEMS] = 0.f; }
    const float4* e4 = (const float4*)(emb + k * 64);
    float s = 0.f;
#pragma unroll
    for (int j = 0; j < 16; ++j) {
        float4 v = e4[j];
        float vv[4] = {v.x, v.y, v.z, v.w};
        ushort4 hv, lv;
        unsigned short h[4], l[4];
#pragma unroll
        for (int t = 0; t < 4; ++t) {
            s = fmaf(vv[t], vv[t], s);
            h[t] = bf16_rne(vv[t]);
            l[t] = bf16_rne(vv[t] - bf16_to_f(h[t]));
        }
        hv.x = h[0]; hv.y = h[1]; hv.z = h[2]; hv.w = h[3];
        lv.x = l[0]; lv.y = l[1]; lv.z = l[2]; lv.w = l[3];
        *(ushort4*)(epack + k * 128 + j * 4)      = hv;
        *(ushort4*)(epack + k * 128 + 64 + j * 4) = lv;
    }
    enorm[k] = s;
}

// Scan: block = 128 px x 256 codes. 4 waves each own 64 codes IN REGISTERS and
// sweep the block's pixels from LDS. Grid 2048 = 512 px-blocks x 4 code-groups.
__global__ __launch_bounds__(256, 2) void vq_scan(const float* __restrict__ z_e,
        const unsigned short* __restrict__ epack, const float* __restrict__ enorm,
        double* __restrict__ pbest, float* __restrict__ pb2) {
    const int tid  = threadIdx.x;
    const int lane = tid & 63;
    const int col  = lane & 15;
    const int g    = lane >> 4;
    const int wv   = __builtin_amdgcn_readfirstlane(tid >> 6);
    const int pxblock = blockIdx.x >> 2;
    const int grp     = blockIdx.x & 3;
    const int cbase   = grp * 256 + wv * 64;   // this wave's 64 codes
    const int pblk    = pxblock * PXB;

    __shared__ __align__(16) unsigned short afrag[PXB * 128];  // px x (hi64|lo64), swizzled
    __shared__ double mrgB[4][PXB];
    __shared__ float  mrgS[4][PXB];

    // ---- stage + convert 128 pixels into LDS (once per block)
    {
        const int lp   = tid & 127;
        const int half = tid >> 7;                 // dims half*32 .. +32
        const int pg   = pblk + lp;
        const float* zb = z_e + (pg >> 12) * 262144 + (pg & 4095);
        const int sx = (lp & 7) << 3;
#pragma unroll
        for (int s8 = 0; s8 < 4; ++s8) {
            const int d0 = half * 32 + s8 * 8;
            short8 H, L;
#pragma unroll
            for (int j = 0; j < 8; ++j) {
                float v = zb[(d0 + j) * 4096];
                unsigned short h = bf16_rne(v);
                H[j] = (short)h;
                L[j] = (short)bf16_rne(v - bf16_to_f(h));
            }
            const int sw = d0 ^ sx;                // 16B-granular XOR swizzle
            *(short8*)&afrag[lp * 128 + sw]      = H;
            *(short8*)&afrag[lp * 128 + 64 + sw] = L;
        }
    }

    // ---- A fragments (codes) - loaded once, resident
    short8 ah[4][2], al[4][2];
    f32x4 enf[4];
    int clo[4][4];
    const int K1 = 1023 - cbase - g * 4;
#pragma unroll
    for (int t = 0; t < 4; ++t) {
        const int code = cbase + t * 16 + col;
        const short8* ph = (const short8*)(epack + code * 128) + g;
        ah[t][0] = ph[0]; ah[t][1] = ph[4];
        al[t][0] = ph[8]; al[t][1] = ph[12];
        const float4 e4 = *(const float4*)(enorm + cbase + t * 16 + g * 4);
        enf[t][0] = -0.5f * e4.x; enf[t][1] = -0.5f * e4.y;
        enf[t][2] = -0.5f * e4.z; enf[t][3] = -0.5f * e4.w;
#pragma unroll
        for (int r = 0; r < 4; ++r) clo[t][r] = K1 - t * 16 - r;
    }
    __syncthreads();

    const f32x4 zero4 = {0.f, 0.f, 0.f, 0.f};
    const int g8 = g * 8;

    // ---- sweep pixels: 8 iters x 16 px; all operands reg/LDS-resident
#pragma unroll 2
    for (int it = 0; it < PXB / 16; ++it) {
        const int lpx = it * 16 + col;             // this lane's pixel (local)
        const int sxp = (lpx & 7) << 3;
        const unsigned short* ap = &afrag[lpx * 128];
        // B fragment: lane's k-group g holds dims g*8..+7 (chunk0), 32+g*8..+7 (chunk1)
        const short8 bh0 = *(const short8*)&ap[(g8        ) ^ sxp];
        const short8 bh1 = *(const short8*)&ap[(32 + g8   ) ^ sxp];
        const short8 bl0 = *(const short8*)&ap[64 + ((g8     ) ^ sxp)];
        const short8 bl1 = *(const short8*)&ap[64 + ((32 + g8) ^ sxp)];

        double B = dpack(-INFINITY, 0u);
        float  S = -INFINITY;
#pragma unroll
        for (int t = 0; t < 4; ++t) {
            f32x4 aA, aB;   // chunk0 / chunk1 independent 3-chains
            aA = __builtin_amdgcn_mfma_f32_16x16x32_bf16(ah[t][0], bh0, enf[t], 0, 0, 0);
            aB = __builtin_amdgcn_mfma_f32_16x16x32_bf16(ah[t][1], bh1, zero4, 0, 0, 0);
            aA = __builtin_amdgcn_mfma_f32_16x16x32_bf16(al[t][0], bh0, aA, 0, 0, 0);
            aB = __builtin_amdgcn_mfma_f32_16x16x32_bf16(al[t][1], bh1, aB, 0, 0, 0);
            aA = __builtin_amdgcn_mfma_f32_16x16x32_bf16(ah[t][0], bl0, aA, 0, 0, 0);
            aB = __builtin_amdgcn_mfma_f32_16x16x32_bf16(ah[t][1], bl1, aB, 0, 0, 0);
#pragma unroll
            for (int r = 0; r < 4; ++r) {
                const float v = aA[r] + aB[r];     // score(code = cbase+t*16+g*4+r, px)
                S = __builtin_amdgcn_fmed3f(dhi(B), S, v);
                B = fmax(B, dpack(v, (unsigned)clo[t][r]));
            }
        }
        // reduce over g (lane bits 4-5): each lane ends with its pixel's result
#pragma unroll
        for (int s = 16; s < 64; s <<= 1) {
            const double ob = __shfl_xor(B, s, 64);
            const float  o2 = __shfl_xor(S, s, 64);
            S = __builtin_amdgcn_fmed3f(dhi(B), dhi(ob), fmaxf(S, o2));
            B = fmax(B, ob);
        }
        if (g == 0) { mrgB[wv][lpx] = B; mrgS[wv][lpx] = S; }
    }

    // ---- merge the 4 waves' 64-code results -> per-(px, 256-code group) partial
    __syncthreads();
    if (tid < PXB) {
        double B = mrgB[0][tid];
        float  S = mrgS[0][tid];
#pragma unroll
        for (int w = 1; w < 4; ++w) {
            const double ob = mrgB[w][tid];
            const float  o2 = mrgS[w][tid];
            S = __builtin_amdgcn_fmed3f(dhi(B), dhi(ob), fmaxf(S, o2));
            B = fmax(B, ob);
        }
        const int pxg = pblk + tid;
        pbest[grp * 65536 + pxg] = B;
        pb2[grp * 65536 + pxg]   = S;
    }
}

// Merge 4 code-group partials per pixel; write index; flag near-ties. Grid 256.
__global__ __launch_bounds__(256) void vq_merge(const double* __restrict__ pbest,
        const float* __restrict__ pb2, float* __restrict__ out,
        int* __restrict__ risky_cnt, int* __restrict__ risky) {
    const int px = blockIdx.x * 256 + threadIdx.x;
    double B = pbest[px];
    float  S = pb2[px];
#pragma unroll
    for (int gq = 1; gq < 4; ++gq) {
        const double ob = pbest[gq * 65536 + px];
        const float  o2 = pb2[gq * 65536 + px];
        S = __builtin_amdgcn_fmed3f(dhi(B), dhi(ob), fmaxf(S, o2));
        B = fmax(B, ob);
    }
    out[ZQ_ELEMS + 1 + px] = (float)(1023 - (int)dlo(B));
    if (dhi(B) - S < EPS_HALF) {
        const int pos = atomicAdd(risky_cnt, 1);
        risky[pos] = px;
    }
}

// Exact fp64 rescore: one wave per flagged item. Grid 512 (2048 waves).
__global__ __launch_bounds__(256) void vq_rescore(const float* __restrict__ z_e,
        const float* __restrict__ emb, float* __restrict__ out,
        const int* __restrict__ cnt, const int* __restrict__ list) {
    const int lane = threadIdx.x & 63;
    const int wid  = (blockIdx.x * 256 + threadIdx.x) >> 6;
    const int nw   = gridDim.x * 4;
    float* idxp = out + ZQ_ELEMS + 1;
    const int n = *cnt;
    for (int item = wid; item < n; item += nw) {
        const int pix = list[item];
        const float* zb = z_e + (pix >> 12) * 262144 + (pix & 4095);
        float f[64];
#pragma unroll
        for (int d = 0; d < 64; ++d) f[d] = zb[d * 4096];
        double best = INFINITY; int bk = KC;
        for (int j = 0; j < 16; ++j) {
            const int k = j * 64 + lane;
            const float* e = emb + k * 64;
            double a0 = 0.0, a1 = 0.0;
#pragma unroll
            for (int d = 0; d < 64; d += 2) {
                double d0 = (double)f[d]     - (double)e[d];
                double d1 = (double)f[d + 1] - (double)e[d + 1];
                a0 = fma(d0, d0, a0);
                a1 = fma(d1, d1, a1);
            }
            double acc = a0 + a1;
            if (acc < best || (acc == best && k < bk)) { best = acc; bk = k; }
        }
        for (int off = 32; off; off >>= 1) {
            double ov = __shfl_down(best, off, 64);
            int    oi = __shfl_down(bk, off, 64);
            if (ov < best || (ov == best && oi < bk)) { best = ov; bk = oi; }
        }
        if (lane == 0) idxp[pix] = (float)bk;
    }
}

// Transpose-gather through LDS: block = 64 pixels. Coalesced everywhere. Grid 1024.
__global__ __launch_bounds__(256) void vq_gather(const float* __restrict__ z_e,
        const float* __restrict__ emb, float* __restrict__ out) {
    __shared__ float zq[64][65];       // +1 pad: conflict-free transpose
    const int tid  = threadIdx.x;
    const int lane = tid & 63;
    const int w    = __builtin_amdgcn_readfirstlane(tid >> 6);
    const int pblk = blockIdx.x * 64;
    const int batch = pblk >> 12;
    const int hw0   = pblk & 4095;
    const float* idxp = out + ZQ_ELEMS + 1;

#pragma unroll
    for (int i = 0; i < 16; ++i) {
        const int p = w * 16 + i;
        const int k = (int)idxp[pblk + p];     // wave-uniform -> broadcast
        zq[p][lane] = emb[k * 64 + lane];
    }
    __syncthreads();

    const int p4 = (tid & 15) * 4;
    const float* zeb = z_e + batch * 262144 + hw0;
    float* ob = out + batch * 262144 + hw0;
    float ss = 0.f;
#pragma unroll
    for (int it = 0; it < 4; ++it) {
        const int d = (tid >> 4) + it * 16;
        float4 q;
        q.x = zq[p4 + 0][d]; q.y = zq[p4 + 1][d];
        q.z = zq[p4 + 2][d]; q.w = zq[p4 + 3][d];
        const float4 z = *(const float4*)(zeb + d * 4096 + p4);
        *(float4*)(ob + d * 4096 + p4) = q;
        const float d0 = q.x - z.x, d1 = q.y - z.y, d2 = q.z - z.z, d3 = q.w - z.w;
        ss += d0 * d0 + d1 * d1 + d2 * d2 + d3 * d3;
    }
    for (int off = 32; off; off >>= 1) ss += __shfl_down(ss, off, 64);
    __shared__ float sred[4];
    if (lane == 0) sred[w] = ss;
    __syncthreads();
    if (tid == 0)
        atomicAdd(out + ZQ_ELEMS,
                  ((sred[0] + sred[1]) + (sred[2] + sred[3])) * (1.25f / (float)ZQ_ELEMS));
}

extern "C" void kernel_launch(void* const* d_in, const int* in_sizes, int n_in,
                              void* d_out, int out_size, void* d_ws, size_t ws_size,
                              hipStream_t stream) {
    const float* z_e = (const float*)d_in[0];
    const float* emb = (const float*)d_in[1];
    float* out = (float*)d_out;
    char* ws = (char*)d_ws;
    unsigned short* epack = (unsigned short*)ws;
    float* enorm     = (float*)(ws + 262144);
    int*   risky_cnt = (int*)(ws + 266240);

    double* pbest = (double*)out;               // out floats [0, 524288)
    float*  pb2   = out + 524288;               // out floats [524288, 786432)
    int*    risky = (int*)(out + 786432);       // out floats [786432, ...)

    vq_prep<<<4, 256, 0, stream>>>(emb, epack, enorm, risky_cnt, out);
    vq_scan<<<2048, 256, 0, stream>>>(z_e, epack, enorm, pbest, pb2);
    vq_merge<<<256, 256, 0, stream>>>(pbest, pb2, out, risky_cnt, risky);
    vq_rescore<<<512, 256, 0, stream>>>(z_e, emb, out, risky_cnt, risky);
    vq_gather<<<1024, 256, 0, stream>>>(z_e, emb, out);
}